// Round 1
// baseline (9549.804 us; speedup 1.0000x reference)
//
#include <hip/hip_runtime.h>
#include <float.h>
#include <math.h>

#define D 512
#define VDIM 512
#define KSEL 32
#define NCHUNKS 32
#define QB 64      // queries per block (4 waves x 16 each)
#define KT 256     // keys per tile
#define DC 32      // d-chunk staged per iteration
#define LROW 36    // padded LDS row stride in floats (16B-aligned, bank-spread)
#define NCAND (NCHUNKS * KSEL)   // 1024 candidates per query

// ---------------- Kernel 1: inverse norms (one wave per row) ----------------
__global__ void k_norms(const float* __restrict__ queries,
                        const float* __restrict__ keys,
                        float* __restrict__ inv_nq, float* __restrict__ inv_nk,
                        int B, int N) {
  const int wid = threadIdx.x >> 6, lane = threadIdx.x & 63;
  const int row = blockIdx.x * 4 + wid;
  if (row >= N + B) return;
  const float* src = (row < N) ? (keys + (size_t)row * D)
                               : (queries + (size_t)(row - N) * D);
  const float4* s4 = (const float4*)src;     // 128 float4 per row
  float4 a = s4[lane], b = s4[lane + 64];
  float ss = a.x*a.x + a.y*a.y + a.z*a.z + a.w*a.w
           + b.x*b.x + b.y*b.y + b.z*b.z + b.w*b.w;
  #pragma unroll
  for (int off = 32; off; off >>= 1) ss += __shfl_xor(ss, off);
  if (lane == 0) {
    float inv = 1.0f / fmaxf(sqrtf(ss), 1e-8f);
    if (row < N) inv_nk[row] = inv; else inv_nq[row - N] = inv;
  }
}

// -------- Kernel 2: fp32 sims (tiled FMA) + per-chunk top-32 per query ------
__global__ __launch_bounds__(256)
void k_sims_topk(const float* __restrict__ queries,
                 const float* __restrict__ keys,
                 const float* __restrict__ inv_nk,
                 float* __restrict__ cand_val, int* __restrict__ cand_idx,
                 int B, int N) {
  __shared__ float q_lds[QB * LROW];
  __shared__ float k_lds[KT * LROW];

  const int t = threadIdx.x;
  const int lane = t & 63;
  const int wid = t >> 6;
  const int qbase = blockIdx.x * QB;
  const int nc = (N + NCHUNKS - 1) / NCHUNKS;   // 3125 for N=100000
  const int c0 = blockIdx.y * nc;
  const int c1 = min(c0 + nc, N);

  // wave-register top-32 per query: lanes 0..31 each own one slot
  float topv[16]; int topi[16]; float curmin[16];
  #pragma unroll
  for (int q = 0; q < 16; ++q) { topv[q] = -FLT_MAX; topi[q] = -1; curmin[q] = -FLT_MAX; }

  #pragma unroll 1
  for (int kt0 = c0; kt0 < c1; kt0 += KT) {
    float acc[16][4];
    #pragma unroll
    for (int q = 0; q < 16; ++q)
      #pragma unroll
      for (int kk = 0; kk < 4; ++kk) acc[q][kk] = 0.f;

    #pragma unroll 1
    for (int dc = 0; dc < D; dc += DC) {
      __syncthreads();
      // stage queries: 64 rows x 32 floats = 512 float4, 2 per thread
      #pragma unroll
      for (int i = 0; i < 2; ++i) {
        int fi = i * 256 + t;
        int q = fi >> 3, d4 = fi & 7;
        float4 v = *(const float4*)&queries[(size_t)(qbase + q) * D + dc + d4 * 4];
        *(float4*)&q_lds[q * LROW + d4 * 4] = v;
      }
      // stage keys: 256 rows x 32 floats = 2048 float4, 8 per thread
      #pragma unroll
      for (int i = 0; i < 8; ++i) {
        int fi = i * 256 + t;
        int k = fi >> 3, d4 = fi & 7;
        int kg = kt0 + k;
        float4 v = make_float4(0.f, 0.f, 0.f, 0.f);
        if (kg < c1) v = *(const float4*)&keys[(size_t)kg * D + dc + d4 * 4];
        *(float4*)&k_lds[k * LROW + d4 * 4] = v;
      }
      __syncthreads();
      // compute: each thread 16 queries x 4 keys (key = kk*64 + lane)
      #pragma unroll
      for (int d4 = 0; d4 < 8; ++d4) {
        float4 kv[4];
        #pragma unroll
        for (int kk = 0; kk < 4; ++kk)
          kv[kk] = *(const float4*)&k_lds[(kk * 64 + lane) * LROW + d4 * 4];
        #pragma unroll
        for (int q = 0; q < 16; ++q) {
          float4 qv = *(const float4*)&q_lds[(wid * 16 + q) * LROW + d4 * 4];
          #pragma unroll
          for (int kk = 0; kk < 4; ++kk) {
            acc[q][kk] = fmaf(qv.x, kv[kk].x, acc[q][kk]);
            acc[q][kk] = fmaf(qv.y, kv[kk].y, acc[q][kk]);
            acc[q][kk] = fmaf(qv.z, kv[kk].z, acc[q][kk]);
            acc[q][kk] = fmaf(qv.w, kv[kk].w, acc[q][kk]);
          }
        }
      }
    }

    // scale by key inverse-norm, mask tail, update running top-32
    float invk[4]; int vld[4];
    #pragma unroll
    for (int kk = 0; kk < 4; ++kk) {
      int kg = kt0 + kk * 64 + lane;
      vld[kk] = (kg < c1);
      invk[kk] = vld[kk] ? inv_nk[kg] : 0.f;
    }
    #pragma unroll
    for (int q = 0; q < 16; ++q) {
      #pragma unroll
      for (int kk = 0; kk < 4; ++kk) {
        float s = vld[kk] ? acc[q][kk] * invk[kk] : -FLT_MAX;
        unsigned long long m = __ballot(s > curmin[q]);
        while (m) {
          int l = __ffsll((unsigned long long)m) - 1; m &= m - 1;
          float v = __shfl(s, l);
          if (v > curmin[q]) {   // uniform branch (v, curmin wave-uniform)
            int ki = kt0 + kk * 64 + l;
            unsigned long long mm = __ballot(lane < 32 && topv[q] == curmin[q]);
            int slot = __ffsll((unsigned long long)mm) - 1;
            if (lane == slot) { topv[q] = v; topi[q] = ki; }
            float mn = (lane < 32) ? topv[q] : FLT_MAX;
            #pragma unroll
            for (int off = 16; off; off >>= 1) mn = fminf(mn, __shfl_xor(mn, off));
            curmin[q] = __shfl(mn, 0);
          }
        }
      }
    }
  }

  // write chunk-local candidates (unsorted)
  if (lane < 32) {
    #pragma unroll 1
    for (int q = 0; q < 16; ++q) {
      int qg = qbase + wid * 16 + q;
      size_t base = (size_t)qg * NCAND + (size_t)blockIdx.y * KSEL + lane;
      cand_val[base] = topv[q];
      cand_idx[base] = topi[q];
    }
  }
}

// ------- Kernel 3: merge candidates -> top-32, softmax, gather values -------
__global__ __launch_bounds__(256)
void k_merge(const float* __restrict__ cand_val, const int* __restrict__ cand_idx,
             const float* __restrict__ inv_nq, const float* __restrict__ values,
             float* __restrict__ out, int B, int N) {
  __shared__ float cv[NCAND]; __shared__ int ci[NCAND];
  __shared__ float rv[256];   __shared__ int rp[256];
  __shared__ float topv[KSEL]; __shared__ int topi[KSEL];
  __shared__ float wsum_s;
  const int t = threadIdx.x;
  const int q = blockIdx.x;
  const float invq = inv_nq[q];
  #pragma unroll
  for (int i = 0; i < 4; ++i) {
    int p = i * 256 + t;
    cv[p] = cand_val[(size_t)q * NCAND + p] * invq;
    ci[p] = cand_idx[(size_t)q * NCAND + p];
  }
  __syncthreads();
  // 32 rounds of block-wide argmax (deterministic tie-break: lowest position)
  for (int r = 0; r < KSEL; ++r) {
    float bv = -FLT_MAX; int bp = 0;
    #pragma unroll
    for (int i = 0; i < 4; ++i) {
      int p = i * 256 + t;
      float v = cv[p];
      if (v > bv) { bv = v; bp = p; }
    }
    rv[t] = bv; rp[t] = bp;
    __syncthreads();
    for (int s = 128; s > 0; s >>= 1) {
      if (t < s) {
        if (rv[t + s] > rv[t] || (rv[t + s] == rv[t] && rp[t + s] < rp[t])) {
          rv[t] = rv[t + s]; rp[t] = rp[t + s];
        }
      }
      __syncthreads();
    }
    if (t == 0) {
      int p = rp[0];
      topv[r] = cv[p]; topi[r] = ci[p];
      cv[p] = -FLT_MAX;
    }
    __syncthreads();
  }
  // softmax weights over the sorted-desc top-32
  if (t == 0) {
    float m = topv[0], sum = 0.f;
    for (int j = 0; j < KSEL; ++j) { float w = expf(topv[j] - m); rv[j] = w; sum += w; }
    wsum_s = sum;
  }
  __syncthreads();
  const float inv_sum = 1.0f / wsum_s;
  float acc0 = 0.f, acc1 = 0.f;
  #pragma unroll 1
  for (int j = 0; j < KSEL; ++j) {
    float w = rv[j];
    const float* vrow = values + (size_t)topi[j] * VDIM;
    acc0 += w * vrow[t];
    acc1 += w * vrow[t + 256];
  }
  out[(size_t)q * VDIM + t] = acc0 * inv_sum;
  out[(size_t)q * VDIM + t + 256] = acc1 * inv_sum;
  if (t < KSEL) out[(size_t)B * VDIM + (size_t)q * KSEL + t] = topv[t];
}

extern "C" void kernel_launch(void* const* d_in, const int* in_sizes, int n_in,
                              void* d_out, int out_size, void* d_ws, size_t ws_size,
                              hipStream_t stream) {
  const float* queries = (const float*)d_in[0];
  const float* keys    = (const float*)d_in[1];
  const float* values  = (const float*)d_in[2];
  const int B = in_sizes[0] / D;     // 2048
  const int N = in_sizes[1] / D;     // 100000
  float* ws = (float*)d_ws;
  float* inv_nk = ws;                         // N floats
  float* inv_nq = ws + N;                     // B floats
  float* cand_val = ws + N + B;               // B*NCAND floats
  int*   cand_idx = (int*)(cand_val + (size_t)B * NCAND);
  float* out = (float*)d_out;

  const int rows = N + B;
  k_norms<<<(rows + 3) / 4, 256, 0, stream>>>(queries, keys, inv_nq, inv_nk, B, N);
  dim3 g2(B / QB, NCHUNKS);
  k_sims_topk<<<g2, 256, 0, stream>>>(queries, keys, inv_nk, cand_val, cand_idx, B, N);
  k_merge<<<B, 256, 0, stream>>>(cand_val, cand_idx, inv_nq, values, out, B, N);
}

// Round 2
// 1157.173 us; speedup vs baseline: 8.2527x; 8.2527x over previous
//
#include <hip/hip_runtime.h>
#include <float.h>
#include <math.h>

#define D 512
#define VDIM 512
#define KSEL 32
#define BM 128
#define BN 128
#define NCH 48
#define CAP 2048
#define TSEL 48
#define TAU 0.11f

typedef short bf16x8 __attribute__((ext_vector_type(8)));
typedef float f32x4 __attribute__((ext_vector_type(4)));
typedef const unsigned int __attribute__((address_space(1))) as1_uint;
typedef unsigned int __attribute__((address_space(3))) as3_uint;

// ---------- Kernel 1: norms + normalized-bf16 conversion (1 wave/row) ------
__global__ __launch_bounds__(256)
void k_prep(const float* __restrict__ queries, const float* __restrict__ keys,
            unsigned short* __restrict__ qbf, unsigned short* __restrict__ kbf,
            float* __restrict__ inv_nq, float* __restrict__ inv_nk, int B, int N) {
  const int wid = threadIdx.x >> 6, lane = threadIdx.x & 63;
  const int row = blockIdx.x * 4 + wid;
  if (row >= N + B) return;
  const bool iskey = row < N;
  const float* src = iskey ? keys + (size_t)row * D : queries + (size_t)(row - N) * D;
  float4 f0 = *(const float4*)(src + lane * 8);
  float4 f1 = *(const float4*)(src + lane * 8 + 4);
  float ss = f0.x*f0.x + f0.y*f0.y + f0.z*f0.z + f0.w*f0.w
           + f1.x*f1.x + f1.y*f1.y + f1.z*f1.z + f1.w*f1.w;
  #pragma unroll
  for (int off = 32; off; off >>= 1) ss += __shfl_xor(ss, off);
  const float inv = 1.0f / fmaxf(sqrtf(ss), 1e-8f);
  float sc[8] = {f0.x, f0.y, f0.z, f0.w, f1.x, f1.y, f1.z, f1.w};
  bf16x8 ov;
  #pragma unroll
  for (int e = 0; e < 8; ++e) {
    unsigned u = __float_as_uint(sc[e] * inv);
    u += 0x7fffu + ((u >> 16) & 1u);            // RNE to bf16
    ov[e] = (short)(u >> 16);
  }
  unsigned short* dst = (iskey ? kbf + (size_t)row * D
                               : qbf + (size_t)(row - N) * D) + lane * 8;
  *(bf16x8*)dst = ov;
  if (lane == 0) { if (iskey) inv_nk[row] = inv; else inv_nq[row - N] = inv; }
}

// ---------- Kernel 2: bf16 MFMA sims + threshold compaction -----------------
__global__ __launch_bounds__(256)
void k_gemm_filter(const unsigned short* __restrict__ qbf,
                   const unsigned short* __restrict__ kbf,
                   float* __restrict__ cand, int* __restrict__ gcnt,
                   int B, int N) {
  __shared__ char ldsA[BM * 64 * 2];   // 16KB, 128B rows, XOR-swizzled chunks
  __shared__ char ldsB[BN * 64 * 2];   // 16KB
  const int t = threadIdx.x;
  const int lane = t & 63, wid = t >> 6;
  const int wr = wid >> 1, wc = wid & 1;
  const int lr = lane & 15, lg = lane >> 4;
  const int qbase = blockIdx.x * BM;
  const int clen = (N + NCH - 1) / NCH;
  const int c0 = blockIdx.y * clen;
  const int c1 = min(c0 + clen, N);

  // staging coords: linear LDS byte lb -> (row, swizzled k-chunk)
  int rowP[4], kofsP[4];
  #pragma unroll
  for (int p = 0; p < 4; ++p) {
    int lb = p * 4096 + t * 16;
    int row = lb >> 7;
    int k16 = ((lb >> 4) & 7) ^ (row & 7);
    rowP[p] = row; kofsP[p] = k16 * 16;
  }

  #pragma unroll 1
  for (int tile = c0; tile < c1; tile += BN) {
    f32x4 acc[4][4];
    #pragma unroll
    for (int m = 0; m < 4; ++m)
      #pragma unroll
      for (int n = 0; n < 4; ++n) acc[m][n] = (f32x4)0.0f;

    #pragma unroll 1
    for (int kt = 0; kt < D / 64; ++kt) {
      __syncthreads();
      #pragma unroll
      for (int p = 0; p < 4; ++p) {
        int arow = min(qbase + rowP[p], B - 1);
        const char* gA = (const char*)qbf + ((size_t)arow * D + kt * 64) * 2 + kofsP[p];
        char* lA = ldsA + p * 4096 + wid * 1024;
        __builtin_amdgcn_global_load_lds((as1_uint*)(const void*)gA, (as3_uint*)(void*)lA, 16, 0, 0);
        int brow = min(tile + rowP[p], N - 1);
        const char* gB = (const char*)kbf + ((size_t)brow * D + kt * 64) * 2 + kofsP[p];
        char* lB = ldsB + p * 4096 + wid * 1024;
        __builtin_amdgcn_global_load_lds((as1_uint*)(const void*)gB, (as3_uint*)(void*)lB, 16, 0, 0);
      }
      __syncthreads();
      #pragma unroll
      for (int h = 0; h < 2; ++h) {
        bf16x8 a[4], b[4];
        #pragma unroll
        for (int m = 0; m < 4; ++m) {
          int r = wr * 64 + m * 16 + lr;
          int byte = r * 128 + ((h * 64 + lg * 16) ^ ((r & 7) << 4));
          a[m] = *(const bf16x8*)(ldsA + byte);
        }
        #pragma unroll
        for (int n = 0; n < 4; ++n) {
          int r = wc * 64 + n * 16 + lr;
          int byte = r * 128 + ((h * 64 + lg * 16) ^ ((r & 7) << 4));
          b[n] = *(const bf16x8*)(ldsB + byte);
        }
        #pragma unroll
        for (int m = 0; m < 4; ++m)
          #pragma unroll
          for (int n = 0; n < 4; ++n)
            acc[m][n] = __builtin_amdgcn_mfma_f32_16x16x32_bf16(a[m], b[n], acc[m][n], 0, 0, 0);
      }
    }
    // epilogue: compact sims >= TAU (C/D layout: col=lane&15, row=(lane>>4)*4+reg)
    #pragma unroll
    for (int m = 0; m < 4; ++m) {
      #pragma unroll
      for (int j = 0; j < 4; ++j) {
        float v0 = acc[m][0][j], v1 = acc[m][1][j], v2 = acc[m][2][j], v3 = acc[m][3][j];
        bool any = (v0 >= TAU) | (v1 >= TAU) | (v2 >= TAU) | (v3 >= TAU);
        if (__ballot(any)) {
          if (any) {
            int qg = qbase + wr * 64 + m * 16 + lg * 4 + j;
            int kb = tile + wc * 64 + lr;
            #pragma unroll
            for (int n = 0; n < 4; ++n) {
              float v = (n == 0) ? v0 : (n == 1) ? v1 : (n == 2) ? v2 : v3;
              int kg = kb + n * 16;
              if (v >= TAU && kg < c1) {
                int pos = atomicAdd(&gcnt[qg], 1);
                if (pos < CAP) {
                  float2 e; e.x = v; e.y = __int_as_float(kg);
                  *(float2*)&cand[((size_t)qg * CAP + pos) * 2] = e;
                }
              }
            }
          }
        }
      }
    }
  }
}

// ---------- Kernel 3: merge -> approx top-48 -> exact rescore -> output -----
__global__ __launch_bounds__(256)
void k_merge_rescore(const float* __restrict__ cand, const int* __restrict__ gcnt,
                     const float* __restrict__ queries, const float* __restrict__ keys,
                     const float* __restrict__ values,
                     const float* __restrict__ inv_nq, const float* __restrict__ inv_nk,
                     float* __restrict__ out, int B, int N) {
  __shared__ float cv[CAP]; __shared__ int ci[CAP];
  __shared__ float qrow[D];
  __shared__ float wv[4]; __shared__ int wp[4];
  __shared__ int sel[TSEL]; __shared__ float exacts[TSEL];
  __shared__ float topv[KSEL]; __shared__ int topi[KSEL];
  __shared__ float wts[KSEL]; __shared__ float inv_sum_s;
  const int t = threadIdx.x, lane = t & 63, wid = t >> 6;
  const int q = blockIdx.x;
  const int cnt = min(gcnt[q], CAP);
  for (int p = t; p < D; p += 256) qrow[p] = queries[(size_t)q * D + p];
  for (int p = t; p < cnt; p += 256) {
    float2 e = *(const float2*)&cand[((size_t)q * CAP + p) * 2];
    cv[p] = e.x; ci[p] = __float_as_int(e.y);
  }
  if (t < TSEL) sel[t] = -1;
  __syncthreads();
  for (int r = 0; r < TSEL; ++r) {
    float bv = -FLT_MAX; int bp = -1;
    for (int p = t; p < cnt; p += 256) { float v = cv[p]; if (v > bv) { bv = v; bp = p; } }
    #pragma unroll
    for (int off = 32; off; off >>= 1) {
      float ov = __shfl_xor(bv, off); int op = __shfl_xor(bp, off);
      if (ov > bv) { bv = ov; bp = op; }
    }
    if (lane == 0) { wv[wid] = bv; wp[wid] = bp; }
    __syncthreads();
    if (t == 0) {
      float fb = wv[0]; int fp = wp[0];
      for (int w = 1; w < 4; ++w) if (wv[w] > fb) { fb = wv[w]; fp = wp[w]; }
      if (fp >= 0) { sel[r] = ci[fp]; cv[fp] = -FLT_MAX; }
    }
    __syncthreads();
  }
  // exact fp32 rescore (12 rows per wave)
  const float invq = inv_nq[q];
  #pragma unroll 1
  for (int i = 0; i < TSEL / 4; ++i) {
    int j = wid * (TSEL / 4) + i;
    int idx = sel[j];
    float dotv = 0.f;
    if (idx >= 0) {
      const float4* kr = (const float4*)(keys + (size_t)idx * D);
      float4 k0 = kr[lane * 2], k1 = kr[lane * 2 + 1];
      float4 q0 = *(const float4*)&qrow[lane * 8];
      float4 q1 = *(const float4*)&qrow[lane * 8 + 4];
      dotv = q0.x*k0.x + q0.y*k0.y + q0.z*k0.z + q0.w*k0.w
           + q1.x*k1.x + q1.y*k1.y + q1.z*k1.z + q1.w*k1.w;
      #pragma unroll
      for (int off = 32; off; off >>= 1) dotv += __shfl_xor(dotv, off);
    }
    if (lane == 0) exacts[j] = (idx >= 0) ? dotv * invq * inv_nk[idx] : -FLT_MAX;
  }
  __syncthreads();
  // exact sorted top-32 (wave 0)
  if (wid == 0) {
    float v = (lane < TSEL) ? exacts[lane] : -FLT_MAX;
    int myi = (lane < TSEL) ? sel[lane] : -1;
    for (int r = 0; r < KSEL; ++r) {
      float bv = v; int bl = lane;
      #pragma unroll
      for (int off = 32; off; off >>= 1) {
        float ov = __shfl_xor(bv, off); int ol = __shfl_xor(bl, off);
        if (ov > bv || (ov == bv && ol < bl)) { bv = ov; bl = ol; }
      }
      if (lane == 0) topv[r] = bv;
      if (lane == bl) { topi[r] = myi; v = -FLT_MAX; }
    }
  }
  __syncthreads();
  if (t == 0) {
    float mx = topv[0], sum = 0.f;
    for (int r = 0; r < KSEL; ++r) { float w = expf(topv[r] - mx); wts[r] = w; sum += w; }
    inv_sum_s = 1.0f / sum;
  }
  __syncthreads();
  const float inv_sum = inv_sum_s;
  float a0 = 0.f, a1 = 0.f;
  #pragma unroll 1
  for (int r = 0; r < KSEL; ++r) {
    const float* vr = values + (size_t)topi[r] * VDIM;
    float w = wts[r];
    a0 += w * vr[t]; a1 += w * vr[t + 256];
  }
  out[(size_t)q * VDIM + t] = a0 * inv_sum;
  out[(size_t)q * VDIM + t + 256] = a1 * inv_sum;
  if (t < KSEL) out[(size_t)B * VDIM + (size_t)q * KSEL + t] = topv[t];
}

extern "C" void kernel_launch(void* const* d_in, const int* in_sizes, int n_in,
                              void* d_out, int out_size, void* d_ws, size_t ws_size,
                              hipStream_t stream) {
  const float* queries = (const float*)d_in[0];
  const float* keys    = (const float*)d_in[1];
  const float* values  = (const float*)d_in[2];
  const int B = in_sizes[0] / D;     // 2048
  const int N = in_sizes[1] / D;     // 100000
  char* ws = (char*)d_ws;
  size_t o = 0;
  unsigned short* kbf = (unsigned short*)(ws + o); o += (size_t)N * D * 2; o = (o + 255) & ~(size_t)255;
  unsigned short* qbf = (unsigned short*)(ws + o); o += (size_t)B * D * 2; o = (o + 255) & ~(size_t)255;
  float* inv_nk = (float*)(ws + o); o += (size_t)N * 4; o = (o + 255) & ~(size_t)255;
  float* inv_nq = (float*)(ws + o); o += (size_t)B * 4; o = (o + 255) & ~(size_t)255;
  int*   gcnt   = (int*)(ws + o);   o += (size_t)B * 4; o = (o + 255) & ~(size_t)255;
  float* cand   = (float*)(ws + o); o += (size_t)B * CAP * 8;
  float* out = (float*)d_out;

  hipMemsetAsync(gcnt, 0, B * sizeof(int), stream);
  k_prep<<<(N + B + 3) / 4, 256, 0, stream>>>(queries, keys, qbf, kbf, inv_nq, inv_nk, B, N);
  dim3 g2((B + BM - 1) / BM, NCH);
  k_gemm_filter<<<g2, 256, 0, stream>>>(qbf, kbf, cand, gcnt, B, N);
  k_merge_rescore<<<B, 256, 0, stream>>>(cand, gcnt, queries, keys, values,
                                         inv_nq, inv_nk, out, B, N);
}